// Round 1
// baseline (350.648 us; speedup 1.0000x reference)
//
#include <hip/hip_runtime.h>
#include <math.h>

#define D_MODEL 512
#define BATCH 8
#define SEQ 512
#define HEAD 64
#define DK 4
#define DV 8
#define HIDD 10

// proj1 tiled-GEMM params
#define MR 32    // rows per block
#define KC 32    // k-chunk
#define NC 128   // cols per block (16 KB W tile -> 20 KB LDS -> 8 blocks/CU)

__device__ __forceinline__ float4 fma4(float s, float4 w, float4 a) {
    a.x = fmaf(s, w.x, a.x); a.y = fmaf(s, w.y, a.y);
    a.z = fmaf(s, w.z, a.z); a.w = fmaf(s, w.w, a.w);
    return a;
}

// ---------------------------------------------------------------------------
// proj1: [4096 x 512] @ {Wq|Wk|Wv} for the SELF stage PLUS the cross-stage
// K/V from x_enc (they only depend on x_enc -> hoisted off the critical
// path). 14 col-jobs x 128 row-blocks = 1792 blocks = 7 blocks/CU
// (vs 2/CU before: Occupancy 16% -> ~80%).
// Outputs head-major: Q/K = [b][h][s][4], V = [b][h][s][8].
// ---------------------------------------------------------------------------
__global__ __launch_bounds__(256, 8) void proj_kernel(
    const float* __restrict__ x, const float* __restrict__ xe,
    const float* __restrict__ Wq, const float* __restrict__ Wk,
    const float* __restrict__ Wv,
    float* __restrict__ Q1, float* __restrict__ K1, float* __restrict__ V1,
    float* __restrict__ Kc, float* __restrict__ Vc)
{
    __shared__ float xt[KC * MR];   // [k][r]  4 KB (transposed)
    __shared__ float wt[KC * NC];   // [k][c] 16 KB

    const int t  = threadIdx.x;
    const int bj = blockIdx.x >> 7;      // 0..13 col-job
    const int br = blockIdx.x & 127;     // row block
    const int r0 = br * MR;

    const float* X; const float* W; int ldw; int c0; float* dst; int vtype;
    if (bj < 2)       { X = x;  W = Wq; ldw = 256; c0 = bj * 128;         dst = Q1; vtype = 0; }
    else if (bj < 4)  { X = x;  W = Wk; ldw = 256; c0 = (bj - 2) * 128;   dst = K1; vtype = 0; }
    else if (bj < 8)  { X = x;  W = Wv; ldw = 512; c0 = (bj - 4) * 128;   dst = V1; vtype = 1; }
    else if (bj < 10) { X = xe; W = Wk; ldw = 256; c0 = (bj - 8) * 128;   dst = Kc; vtype = 0; }
    else              { X = xe; W = Wv; ldw = 512; c0 = (bj - 10) * 128;  dst = Vc; vtype = 1; }

    const int cq = t & 31;          // cols cq*4..+3
    const int rr = t >> 5;          // rows rr*4..+3
    const int rs = t & 31;          // x staging: row
    const int kq = t >> 5;          // x staging: k-quad

    float4 acc[4];
#pragma unroll
    for (int r = 0; r < 4; ++r) acc[r] = make_float4(0.f, 0.f, 0.f, 0.f);

    for (int kc = 0; kc < D_MODEL; kc += KC) {
        // stage x tile transposed [k][r]
        const float4 xa = *(const float4*)(X + (long)(r0 + rs) * D_MODEL + kc + kq * 4);
        xt[(kq * 4 + 0) * MR + rs] = xa.x;
        xt[(kq * 4 + 1) * MR + rs] = xa.y;
        xt[(kq * 4 + 2) * MR + rs] = xa.z;
        xt[(kq * 4 + 3) * MR + rs] = xa.w;

        // stage W tile: 32 rows x 128 cols; wave reads 2 contiguous 512B rows
#pragma unroll
        for (int i = 0; i < 4; ++i) {
            const int row = i * 8 + (t >> 5);
            *(float4*)(wt + row * NC + (t & 31) * 4) =
                *(const float4*)(W + (long)(kc + row) * ldw + c0 + (t & 31) * 4);
        }
        __syncthreads();

#pragma unroll 4
        for (int k = 0; k < KC; ++k) {
            const float4 w4 = *(const float4*)(wt + k * NC + cq * 4);
            const float4 x4 = *(const float4*)(xt + k * MR + rr * 4);
            acc[0] = fma4(x4.x, w4, acc[0]);
            acc[1] = fma4(x4.y, w4, acc[1]);
            acc[2] = fma4(x4.z, w4, acc[2]);
            acc[3] = fma4(x4.w, w4, acc[3]);
        }
        __syncthreads();
    }

    const int b  = r0 >> 9;
    const int sb = (r0 & 511) + rr * 4;
    if (vtype == 0) {
        const int h = (c0 >> 2) + cq;   // each f4 = a full (s, head) Q/K row
#pragma unroll
        for (int r = 0; r < 4; ++r)
            *(float4*)(dst + (((long)b * HEAD + h) * SEQ + sb + r) * 4) = acc[r];
    } else {
        const int col = c0 + cq * 4;
        const int h = col >> 3;
        const int off = col & 4;        // 0 or 4
#pragma unroll
        for (int r = 0; r < 4; ++r)
            *(float4*)(dst + (((long)b * HEAD + h) * SEQ + sb + r) * 8 + off) = acc[r];
    }
}

// ---------------------------------------------------------------------------
// proj2: Q only (attn1 output A is ONLY consumed as Q of stage 2).
// Split-K x2: kh=0 writes Qa, kh=1 writes Qb; attn adds them on load.
// 128 rowblk x 4 coljobs(NC=64) x 2 khalf = 1024 blocks.
// ---------------------------------------------------------------------------
__global__ __launch_bounds__(256, 8) void proj2_kernel(
    const float* __restrict__ A, const float* __restrict__ Wq,
    float* __restrict__ Qa, float* __restrict__ Qb)
{
    __shared__ float xt[KC * MR];   // 4 KB
    __shared__ float wt[KC * 64];   // 8 KB

    const int t  = threadIdx.x;
    const int kh = blockIdx.x & 1;
    const int bj = (blockIdx.x >> 1) & 3;
    const int br = blockIdx.x >> 3;
    const int r0 = br * MR;
    const int c0 = bj * 64;
    const int kb = kh * 256;
    float* dst = kh ? Qb : Qa;

    const int cq = t & 15;          // cols cq*4..+3 (64 cols)
    const int rr = t >> 4;          // rows rr*2..+1
    const int rs = t & 31, kq = t >> 5;

    float4 acc[2];
    acc[0] = make_float4(0.f, 0.f, 0.f, 0.f);
    acc[1] = acc[0];

    for (int kc = 0; kc < 256; kc += KC) {
        const float4 xa = *(const float4*)(A + (long)(r0 + rs) * D_MODEL + kb + kc + kq * 4);
        xt[(kq * 4 + 0) * MR + rs] = xa.x;
        xt[(kq * 4 + 1) * MR + rs] = xa.y;
        xt[(kq * 4 + 2) * MR + rs] = xa.z;
        xt[(kq * 4 + 3) * MR + rs] = xa.w;
#pragma unroll
        for (int i = 0; i < 2; ++i) {
            const int row = i * 16 + (t >> 4);
            *(float4*)(wt + row * 64 + (t & 15) * 4) =
                *(const float4*)(Wq + (long)(kb + kc + row) * 256 + c0 + (t & 15) * 4);
        }
        __syncthreads();
#pragma unroll 4
        for (int k = 0; k < KC; ++k) {
            const float4 w4 = *(const float4*)(wt + k * 64 + cq * 4);
            const float2 x2 = *(const float2*)(xt + k * MR + rr * 2);
            acc[0] = fma4(x2.x, w4, acc[0]);
            acc[1] = fma4(x2.y, w4, acc[1]);
        }
        __syncthreads();
    }

    const int b  = r0 >> 9;
    const int sb = (r0 & 511) + rr * 2;
    const int h  = (c0 >> 2) + cq;
#pragma unroll
    for (int r = 0; r < 2; ++r)
        *(float4*)(dst + (((long)b * HEAD + h) * SEQ + sb + r) * 4) = acc[r];
}

// ---------------------------------------------------------------------------
// Attention, flash-decode split-K x2: block = (bh, qhalf, khalf), grid 2048
// (8 blocks/CU, 12 KB LDS -> 8 waves/SIMD possible vs structural 4 before).
// Scores are in log2 domain (log2e folded into Q); masked scores are
// EXACTLY 0 and participate (faithful multiplicative-tril quirk) -- no
// divergent tail, no lump/suffix machinery. Writes unnormalized partials.
// ---------------------------------------------------------------------------
template <bool MASKED>
__device__ __forceinline__ void attn_scan(
    const float* __restrict__ Kl, const float* __restrict__ Vl, const int qb,
    const float q0, const float q1, const float q2, const float q3,
    float& m, float& l, float (&a)[8])
{
    for (int s0 = 0; s0 < 256; s0 += 8) {
        float sc[8];
#pragma unroll
        for (int i = 0; i < 8; ++i) {
            const float4 k4 = *(const float4*)(Kl + (s0 + i) * DK);
            const float d = fmaf(q0, k4.x, fmaf(q1, k4.y, fmaf(q2, k4.z, q3 * k4.w)));
            sc[i] = (MASKED && (s0 + i) > qb) ? 0.f : d;
        }
        const float gm = fmaxf(fmaxf(fmaxf(sc[0], sc[1]), fmaxf(sc[2], sc[3])),
                               fmaxf(fmaxf(sc[4], sc[5]), fmaxf(sc[6], sc[7])));
        if (gm > m) {
            const float scale = __builtin_amdgcn_exp2f(m - gm);  // exp2(-inf)=0
            l *= scale;
#pragma unroll
            for (int r = 0; r < 8; ++r) a[r] *= scale;
            m = gm;
        }
#pragma unroll
        for (int i = 0; i < 8; ++i) {
            const float p = __builtin_amdgcn_exp2f(sc[i] - m);
            l += p;
            const float4 v0 = *(const float4*)(Vl + (s0 + i) * DV);
            const float4 v1 = *(const float4*)(Vl + (s0 + i) * DV + 4);
            a[0] = fmaf(p, v0.x, a[0]); a[1] = fmaf(p, v0.y, a[1]);
            a[2] = fmaf(p, v0.z, a[2]); a[3] = fmaf(p, v0.w, a[3]);
            a[4] = fmaf(p, v1.x, a[4]); a[5] = fmaf(p, v1.y, a[5]);
            a[6] = fmaf(p, v1.z, a[6]); a[7] = fmaf(p, v1.w, a[7]);
        }
    }
}

__global__ __launch_bounds__(256, 8) void attn_kernel(
    const float* __restrict__ Qa, const float* __restrict__ Qb,
    const float* __restrict__ K2, const float* __restrict__ V2,
    float* __restrict__ PA, float* __restrict__ PM, const int causal)
{
    __shared__ float Kl[256 * DK];   // 4 KB
    __shared__ float Vl[256 * DV];   // 8 KB

    const int t  = threadIdx.x;
    const int bh = blockIdx.x >> 2;
    const int qh = (blockIdx.x >> 1) & 1;
    const int kh = blockIdx.x & 1;

    ((float4*)Kl)[t] = ((const float4*)(K2 + ((long)bh * SEQ + kh * 256) * DK))[t];
    const float4* Vs = (const float4*)(V2 + ((long)bh * SEQ + kh * 256) * DV);
    ((float4*)Vl)[t]       = Vs[t];
    ((float4*)Vl)[t + 256] = Vs[t + 256];

    const int q = qh * 256 + t;
    float4 qv = *(const float4*)(Qa + ((long)bh * SEQ + q) * DK);
    if (Qb) {                        // split-K projected Q: sum halves
        const float4 qw = *(const float4*)(Qb + ((long)bh * SEQ + q) * DK);
        qv.x += qw.x; qv.y += qw.y; qv.z += qw.z; qv.w += qw.w;
    }
    const float cf = 0.5f * 1.44269504088896340736f;  // 1/sqrt(DK) * log2(e)
    const float q0 = qv.x * cf, q1 = qv.y * cf, q2 = qv.z * cf, q3 = qv.w * cf;

    __syncthreads();

    float m = -INFINITY, l = 0.f, a[8];
#pragma unroll
    for (int r = 0; r < 8; ++r) a[r] = 0.f;

    if (causal)
        attn_scan<true >(Kl, Vl, q - kh * 256, q0, q1, q2, q3, m, l, a);
    else
        attn_scan<false>(Kl, Vl, 255,          q0, q1, q2, q3, m, l, a);

    const long p = ((long)(bh * 2 + kh)) * SEQ + q;
    *(float4*)(PA + p * 8)     = make_float4(a[0], a[1], a[2], a[3]);
    *(float4*)(PA + p * 8 + 4) = make_float4(a[4], a[5], a[6], a[7]);
    *(float2*)(PM + p * 2)     = make_float2(m, l);
}

// ---------------------------------------------------------------------------
// Combine the two K-half partials -> row-major A [b][s][512] (stage 1 only;
// stage 2's combine is fused into ln_mlp).
// ---------------------------------------------------------------------------
__global__ __launch_bounds__(256) void combine_kernel(
    const float* __restrict__ PA, const float* __restrict__ PM,
    float* __restrict__ A)
{
    const int tid = blockIdx.x * 256 + threadIdx.x;   // 0..262143
    const int bh  = tid >> 9;
    const int q   = tid & 511;
    const long p0 = ((long)bh * 2 + 0) * SEQ + q;
    const long p1 = ((long)bh * 2 + 1) * SEQ + q;
    const float2 ml0 = *(const float2*)(PM + p0 * 2);
    const float2 ml1 = *(const float2*)(PM + p1 * 2);
    const float M  = fmaxf(ml0.x, ml1.x);
    float w0 = __builtin_amdgcn_exp2f(ml0.x - M);
    float w1 = __builtin_amdgcn_exp2f(ml1.x - M);
    const float inv = 1.0f / fmaf(ml0.y, w0, ml1.y * w1);
    w0 *= inv; w1 *= inv;
    const float4 x0 = *(const float4*)(PA + p0 * 8);
    const float4 x1 = *(const float4*)(PA + p0 * 8 + 4);
    const float4 y0 = *(const float4*)(PA + p1 * 8);
    const float4 y1 = *(const float4*)(PA + p1 * 8 + 4);
    const int b = bh >> 6, h = bh & 63;
    float* dst = A + ((long)b * SEQ + q) * D_MODEL + h * DV;
    *(float4*)(dst)     = make_float4(x0.x*w0 + y0.x*w1, x0.y*w0 + y0.y*w1,
                                      x0.z*w0 + y0.z*w1, x0.w*w0 + y0.w*w1);
    *(float4*)(dst + 4) = make_float4(x1.x*w0 + y1.x*w1, x1.y*w0 + y1.y*w1,
                                      x1.z*w0 + y1.z*w1, x1.w*w0 + y1.w*w1);
}

// ---------------------------------------------------------------------------
// Fused stage-2 combine + residual + LayerNorm + MLP (512 -> 10 -> 512).
// One WAVE per row; lane == head (e0 = lane*8 spans exactly head `lane`),
// so the split-K combine is a per-lane read of the two partials.
// ---------------------------------------------------------------------------
__global__ __launch_bounds__(256) void ln_mlp_kernel(
    const float* __restrict__ x,
    const float* __restrict__ PA, const float* __restrict__ PM,
    const float* __restrict__ g, const float* __restrict__ beta,
    const float* __restrict__ w1, const float* __restrict__ b1,
    const float* __restrict__ w2, const float* __restrict__ b2,
    float* __restrict__ out)
{
    const int t = threadIdx.x;
    const int lane = t & 63;
    const int row = blockIdx.x * 4 + (t >> 6);
    const int b = row >> 9, q = row & 511;
    const long base = (long)row * D_MODEL;
    const int e0 = lane * 8;

    // inline combine of attn2 partials (head h == lane)
    const long p0 = (((long)b * HEAD + lane) * 2 + 0) * SEQ + q;
    const long p1 = (((long)b * HEAD + lane) * 2 + 1) * SEQ + q;
    const float2 ml0 = *(const float2*)(PM + p0 * 2);
    const float2 ml1 = *(const float2*)(PM + p1 * 2);
    const float M  = fmaxf(ml0.x, ml1.x);
    float cw0 = __builtin_amdgcn_exp2f(ml0.x - M);
    float cw1 = __builtin_amdgcn_exp2f(ml1.x - M);
    const float inv = 1.0f / fmaf(ml0.y, cw0, ml1.y * cw1);
    cw0 *= inv; cw1 *= inv;
    const float4 fa0 = *(const float4*)(PA + p0 * 8);
    const float4 fa1 = *(const float4*)(PA + p0 * 8 + 4);
    const float4 fb0 = *(const float4*)(PA + p1 * 8);
    const float4 fb1 = *(const float4*)(PA + p1 * 8 + 4);

    const float4 xa = *(const float4*)(x + base + e0);
    const float4 xb = *(const float4*)(x + base + e0 + 4);
    float z[8] = {
        xa.x + fa0.x*cw0 + fb0.x*cw1, xa.y + fa0.y*cw0 + fb0.y*cw1,
        xa.z + fa0.z*cw0 + fb0.z*cw1, xa.w + fa0.w*cw0 + fb0.w*cw1,
        xb.x + fa1.x*cw0 + fb1.x*cw1, xb.y + fa1.y*cw0 + fb1.y*cw1,
        xb.z + fa1.z*cw0 + fb1.z*cw1, xb.w + fa1.w*cw0 + fb1.w*cw1};

    float sum = 0.f;
#pragma unroll
    for (int j = 0; j < 8; ++j) sum += z[j];
#pragma unroll
    for (int o = 32; o > 0; o >>= 1) sum += __shfl_xor(sum, o);
    const float mu = sum * (1.0f / 512.0f);

    float d[8], ss = 0.f;
#pragma unroll
    for (int j = 0; j < 8; ++j) { d[j] = z[j] - mu; ss += d[j] * d[j]; }
#pragma unroll
    for (int o = 32; o > 0; o >>= 1) ss += __shfl_xor(ss, o);
    const float rs = rsqrtf(ss * (1.0f / 512.0f) + 1e-5f);

    const float4 ga = *(const float4*)(g + e0);
    const float4 gb = *(const float4*)(g + e0 + 4);
    const float4 ba = *(const float4*)(beta + e0);
    const float4 bb = *(const float4*)(beta + e0 + 4);
    const float gg[8] = {ga.x,ga.y,ga.z,ga.w,gb.x,gb.y,gb.z,gb.w};
    const float bt[8] = {ba.x,ba.y,ba.z,ba.w,bb.x,bb.y,bb.z,bb.w};
    float y[8];
#pragma unroll
    for (int j = 0; j < 8; ++j) y[j] = d[j] * rs * gg[j] + bt[j];

    float part[HIDD];
#pragma unroll
    for (int i = 0; i < HIDD; ++i) {
        const float4 wa = *(const float4*)(w1 + i * 512 + e0);
        const float4 wb = *(const float4*)(w1 + i * 512 + e0 + 4);
        part[i] = y[0]*wa.x + y[1]*wa.y + y[2]*wa.z + y[3]*wa.w
                + y[4]*wb.x + y[5]*wb.y + y[6]*wb.z + y[7]*wb.w;
    }
#pragma unroll
    for (int i = 0; i < HIDD; ++i)
#pragma unroll
        for (int o = 32; o > 0; o >>= 1) part[i] += __shfl_xor(part[i], o);

    float hv[HIDD];
#pragma unroll
    for (int i = 0; i < HIDD; ++i) hv[i] = fmaxf(part[i] + b1[i], 0.f);

    const float4 b2a = *(const float4*)(b2 + e0);
    const float4 b2b = *(const float4*)(b2 + e0 + 4);
    float o8[8] = {b2a.x,b2a.y,b2a.z,b2a.w,b2b.x,b2b.y,b2b.z,b2b.w};
#pragma unroll
    for (int j = 0; j < 8; ++j) {
        const float* wr = w2 + (long)(e0 + j) * 10;   // 8B-aligned (40B rows)
        const float2 wA = *(const float2*)(wr);
        const float2 wB = *(const float2*)(wr + 2);
        const float2 wC = *(const float2*)(wr + 4);
        const float2 wD = *(const float2*)(wr + 6);
        const float2 wE = *(const float2*)(wr + 8);
        o8[j] += hv[0]*wA.x + hv[1]*wA.y + hv[2]*wB.x + hv[3]*wB.y
               + hv[4]*wC.x + hv[5]*wC.y + hv[6]*wD.x + hv[7]*wD.y
               + hv[8]*wE.x + hv[9]*wE.y;
    }

    *(float4*)(out + base + e0)     = make_float4(o8[0], o8[1], o8[2], o8[3]);
    *(float4*)(out + base + e0 + 4) = make_float4(o8[4], o8[5], o8[6], o8[7]);
}

extern "C" void kernel_launch(void* const* d_in, const int* in_sizes, int n_in,
                              void* d_out, int out_size, void* d_ws, size_t ws_size,
                              hipStream_t stream) {
    (void)in_sizes; (void)n_in; (void)out_size; (void)ws_size;
    const float* x    = (const float*)d_in[0];
    const float* xenc = (const float*)d_in[1];
    const float* Wq   = (const float*)d_in[2];
    const float* Wk   = (const float*)d_in[3];
    const float* Wv   = (const float*)d_in[4];
    const float* ln_g = (const float*)d_in[5];
    const float* ln_b = (const float*)d_in[6];
    const float* w1   = (const float*)d_in[7];
    const float* b1   = (const float*)d_in[8];
    const float* w2   = (const float*)d_in[9];
    const float* b2   = (const float*)d_in[10];
    float* out = (float*)d_out;

    // Workspace layout (floats; 12,582,912 total = 48 MiB):
    float* ws = (float*)d_ws;
    float* Q1 = ws;                    // [0M,1M)   self Q   (head-major)
    float* K1 = ws + 1048576;          // [1M,2M)   self K
    float* V1 = ws + 2097152;          // [2M,4M)   self V
    float* Kc = ws + 4194304;          // [4M,5M)   cross K (from x_enc)
    float* Vc = ws + 5242880;          // [5M,7M)   cross V
    float* PA = ws + 7340032;          // [7M,11M)  split-K partial acc [bh][kh][q][8]
    float* PM = ws + 11534336;         // [11M,12M) split-K partial (m,l) [bh][kh][q][2]
    // aliases (regions dead by the time they're reused):
    float* A  = K1;                    // [1M,3M)   attn1 out, row-major (K1/V1 dead)
    float* Qa = Q1;                    // [0M,1M)   stage-2 Q, K-half 0  (Q1 dead)
    float* Qb = ws + 3145728;          // [3M,4M)   stage-2 Q, K-half 1  (V1 tail dead)

    // Stage 1 projections + cross-stage K/V (x_enc-only -> hoisted here)
    proj_kernel<<<dim3(1792), 256, 0, stream>>>(x, xenc, Wq, Wk, Wv,
                                                Q1, K1, V1, Kc, Vc);
    // Self-attention (causal multiplicative-mask quirk), split-K x2
    attn_kernel<<<dim3(2048), 256, 0, stream>>>(Q1, nullptr, K1, V1, PA, PM, 1);
    combine_kernel<<<dim3(1024), 256, 0, stream>>>(PA, PM, A);
    // Stage 2: only Q remains (A is consumed solely as stage-2 Q)
    proj2_kernel<<<dim3(1024), 256, 0, stream>>>(A, Wq, Qa, Qb);
    attn_kernel<<<dim3(2048), 256, 0, stream>>>(Qa, Qb, Kc, Vc, PA, PM, 0);
    // Stage-2 combine fused into residual+LN+MLP (lane == head)
    ln_mlp_kernel<<<dim3(1024), 256, 0, stream>>>(x, PA, PM, ln_g, ln_b,
                                                  w1, b1, w2, b2, out);
}